// Round 11
// baseline (302.558 us; speedup 1.0000x reference)
//
#include <hip/hip_runtime.h>
#include <math.h>

#define N_NODES 50000
#define N_EDGES 800000
#define ET (N_EDGES + N_NODES)   // 850000 incl. self-loops
#define KD 128
#define Z 32
#define NBS ((N_NODES + 1023) / 1024)
#define SH 7
#define BW 128                              // nodes per bucket
#define NBUCK ((N_NODES + BW - 1) / BW)     // 391
#define CHUNK 2048
#define NBLKA ((ET + CHUNK - 1) / CHUNK)    // 416 chunks
#define MTOT (NBUCK * NBLKA)                // 162,656
#define MBS ((MTOT + 1023) / 1024)          // 159

typedef __attribute__((ext_vector_type(8))) short bf16x8;
typedef __attribute__((ext_vector_type(4))) float f32x4;

static __device__ __forceinline__ float lrelu(float x){ return x > 0.f ? x : 0.2f*x; }
static __device__ __forceinline__ float bf2f(unsigned int u16){ return __uint_as_float(u16 << 16); }
static __device__ __forceinline__ unsigned short f2bf(float f){
  unsigned int x = __float_as_uint(f);
  return (unsigned short)((x + 0x7fffu + ((x >> 16) & 1u)) >> 16);   // RNE
}

// ---------- CSR build: counting sort, NO global atomics ----------
__global__ __launch_bounds__(256) void bhistA_kernel(const int* __restrict__ edges, int* __restrict__ M){
  int k = blockIdx.x, t = threadIdx.x;
  __shared__ int cnt[NBUCK];
  for(int b = t; b < NBUCK; b += 256) cnt[b] = 0;
  __syncthreads();
  int base = k*CHUNK;
  int lim = min(base + CHUNK, ET);
  for(int i = base + t; i < lim; i += 256){
    int d = (i < N_EDGES) ? edges[N_EDGES + i] : (i - N_EDGES);
    atomicAdd(&cnt[d >> SH], 1);
  }
  __syncthreads();
  for(int b = t; b < NBUCK; b += 256) M[b*NBLKA + k] = cnt[b];
}

__global__ __launch_bounds__(256) void scanM1_kernel(const int* __restrict__ M, int* __restrict__ bsumM){
  int b = blockIdx.x, t = threadIdx.x;
  int base = b*1024 + t*4;
  int s = 0;
  #pragma unroll
  for(int i=0;i<4;i++){ int n = base+i; if(n < MTOT) s += M[n]; }
  for(int off=32; off; off>>=1) s += __shfl_xor(s, off);
  __shared__ int ws[4];
  if((t&63)==0) ws[t>>6] = s;
  __syncthreads();
  if(t==0) bsumM[b] = ws[0]+ws[1]+ws[2]+ws[3];
}

__global__ __launch_bounds__(256) void scanM2_kernel(const int* __restrict__ bsumM, int* __restrict__ bpreM){
  __shared__ int sm[256];
  int t = threadIdx.x;
  int v = (t < MBS) ? bsumM[t] : 0;
  sm[t] = v;
  __syncthreads();
  for(int off=1; off<256; off<<=1){
    int u = (t >= off) ? sm[t-off] : 0;
    __syncthreads();
    sm[t] += u;
    __syncthreads();
  }
  if(t < MBS) bpreM[t] = sm[t] - v;
}

__global__ __launch_bounds__(256) void scanM3_kernel(const int* __restrict__ M, const int* __restrict__ bpreM,
                                                     int* __restrict__ Mpos){
  int b = blockIdx.x, t = threadIdx.x;
  int lane = t & 63, wv = t >> 6;
  int base = b*1024 + t*4;
  int d[4]; int s = 0;
  #pragma unroll
  for(int i=0;i<4;i++){ int n = base+i; d[i] = (n < MTOT) ? M[n] : 0; s += d[i]; }
  int v = s;
  for(int off=1; off<64; off<<=1){
    int u = __shfl_up(v, off);
    if(lane >= off) v += u;
  }
  int texcl = v - s;
  __shared__ int wtot[4];
  if(lane == 63) wtot[wv] = v;
  __syncthreads();
  int woff = 0;
  for(int i=0;i<wv;i++) woff += wtot[i];
  int run = bpreM[b] + woff + texcl;
  #pragma unroll
  for(int i=0;i<4;i++){
    int n = base+i;
    if(n < MTOT){ Mpos[n] = run; run += d[i]; }
  }
}

__global__ __launch_bounds__(256) void bplaceA_kernel(const int* __restrict__ edges, const int* __restrict__ Mpos,
                                                      int2* __restrict__ etmp){
  int k = blockIdx.x, t = threadIdx.x;
  __shared__ int cur[NBUCK];
  for(int b = t; b < NBUCK; b += 256) cur[b] = Mpos[b*NBLKA + k];
  __syncthreads();
  int base = k*CHUNK;
  int lim = min(base + CHUNK, ET);
  for(int i = base + t; i < lim; i += 256){
    int s, d;
    if(i < N_EDGES){ s = edges[i]; d = edges[N_EDGES+i]; } else { s = d = i - N_EDGES; }
    int pos = atomicAdd(&cur[d >> SH], 1);
    etmp[pos] = make_int2(s, d);
  }
}

__global__ __launch_bounds__(256) void bhist2_kernel(const int* __restrict__ Mpos, const int2* __restrict__ etmp,
                                                     int* __restrict__ deg){
  int b = blockIdx.x, t = threadIdx.x;
  __shared__ int cnt[BW];
  if(t < BW) cnt[t] = 0;
  __syncthreads();
  int beg = Mpos[b*NBLKA];
  int end = (b+1 < NBUCK) ? Mpos[(b+1)*NBLKA] : ET;
  for(int i = beg + t; i < end; i += 256) atomicAdd(&cnt[etmp[i].y & (BW-1)], 1);
  __syncthreads();
  if(t < BW){
    int node = b*BW + t;
    if(node < N_NODES) deg[node] = cnt[t];
  }
}

__global__ __launch_bounds__(256) void scan1_kernel(const int* __restrict__ deg, int* __restrict__ bsum){
  int b = blockIdx.x, t = threadIdx.x;
  int base = b*1024 + t*4;
  int s = 0;
  #pragma unroll
  for(int i=0;i<4;i++){ int n = base+i; if(n < N_NODES) s += deg[n]; }
  for(int off=32; off; off>>=1) s += __shfl_xor(s, off);
  __shared__ int ws[4];
  if((t&63)==0) ws[t>>6] = s;
  __syncthreads();
  if(t==0) bsum[b] = ws[0]+ws[1]+ws[2]+ws[3];
}

__global__ __launch_bounds__(64) void scan2_kernel(const int* __restrict__ bsum, int* __restrict__ bpre){
  int t = threadIdx.x;
  int x = (t < NBS) ? bsum[t] : 0;
  int v = x;
  for(int off=1; off<64; off<<=1){
    int u = __shfl_up(v, off);
    if(t >= off) v += u;
  }
  if(t < NBS) bpre[t] = v - x;
}

__global__ __launch_bounds__(256) void scan3_kernel(const int* __restrict__ deg, const int* __restrict__ bpre,
                                                    int* __restrict__ rowptr){
  int b = blockIdx.x, t = threadIdx.x;
  int lane = t & 63, wv = t >> 6;
  int base = b*1024 + t*4;
  int d[4]; int s = 0;
  #pragma unroll
  for(int i=0;i<4;i++){ int n = base+i; d[i] = (n < N_NODES) ? deg[n] : 0; s += d[i]; }
  int v = s;
  for(int off=1; off<64; off<<=1){
    int u = __shfl_up(v, off);
    if(lane >= off) v += u;
  }
  int texcl = v - s;
  __shared__ int wtot[4];
  if(lane == 63) wtot[wv] = v;
  __syncthreads();
  int woff = 0;
  for(int i=0;i<wv;i++) woff += wtot[i];
  int run = bpre[b] + woff + texcl;
  #pragma unroll
  for(int i=0;i<4;i++){
    int n = base+i;
    if(n < N_NODES){ rowptr[n] = run; run += d[i]; }
  }
  if(b == 0 && t == 0) rowptr[N_NODES] = ET;
}

__global__ __launch_bounds__(256) void bplace_kernel(const int* __restrict__ Mpos, const int2* __restrict__ etmp,
                                                     const int* __restrict__ rowptr, int2* __restrict__ epair){
  int b = blockIdx.x, t = threadIdx.x;
  __shared__ int lcur[BW];
  if(t < BW){
    int node = b*BW + t;
    lcur[t] = (node < N_NODES) ? rowptr[node] : 0;
  }
  __syncthreads();
  int beg = Mpos[b*NBLKA];
  int end = (b+1 < NBUCK) ? Mpos[(b+1)*NBLKA] : ET;
  for(int i = beg + t; i < end; i += 256){
    int2 e = etmp[i];
    int pos = atomicAdd(&lcur[e.y & (BW-1)], 1);
    epair[pos] = e;
  }
}

// ---------- W -> bf16 converter ----------
__global__ __launch_bounds__(256) void wconv_kernel(const float* __restrict__ W1,
                                                    const float* __restrict__ Wmu, const float* __restrict__ Wst,
                                                    unsigned short* __restrict__ Wb1, unsigned short* __restrict__ Wb2){
  int i = blockIdx.x*256 + threadIdx.x;
  if(i < 128*KD) Wb1[i] = f2bf(W1[i]);
  if(i < 64*KD) Wb2[i] = f2bf(i < 32*KD ? Wmu[i] : Wst[i - 32*KD]);
}

// ---------- MFMA matmul (m97-verified layout); no LDS ----------
template<int OC, bool XBF16>
__global__ __launch_bounds__(256) void mmt_kernel(const void* __restrict__ Xv,
                                                  const unsigned short* __restrict__ Wb,
                                                  unsigned short* __restrict__ outb){
  constexpr int CT = OC/16;
  int t = threadIdx.x;
  int w = t >> 6, L = t & 63;
  int col = L & 15, quad = L >> 4;
  int row0 = blockIdx.x*64 + w*16;
  int rA = row0 + col;
  if(rA >= N_NODES) rA = N_NODES-1;

  f32x4 acc[CT];
  #pragma unroll
  for(int ct=0;ct<CT;ct++) acc[ct] = (f32x4){0.f,0.f,0.f,0.f};

  #pragma unroll
  for(int kc=0;kc<4;kc++){
    int k0 = kc*32 + quad*8;
    bf16x8 a;
    if(XBF16){
      a = *(const bf16x8*)((const unsigned short*)Xv + (size_t)rA*KD + k0);
    } else {
      const float* Xf = (const float*)Xv + (size_t)rA*KD + k0;
      float4 p = *(const float4*)Xf;
      float4 q = *(const float4*)(Xf + 4);
      a[0] = (short)f2bf(p.x); a[1] = (short)f2bf(p.y);
      a[2] = (short)f2bf(p.z); a[3] = (short)f2bf(p.w);
      a[4] = (short)f2bf(q.x); a[5] = (short)f2bf(q.y);
      a[6] = (short)f2bf(q.z); a[7] = (short)f2bf(q.w);
    }
    #pragma unroll
    for(int ct=0;ct<CT;ct++){
      bf16x8 b = *(const bf16x8*)(Wb + (size_t)(ct*16 + col)*KD + k0);
      acc[ct] = __builtin_amdgcn_mfma_f32_16x16x32_bf16(a, b, acc[ct], 0, 0, 0);
    }
  }

  #pragma unroll
  for(int ct=0;ct<CT;ct++){
    #pragma unroll
    for(int r=0;r<4;r++){
      int row = row0 + quad*4 + r;
      if(row < N_NODES) outb[(size_t)row*OC + ct*16 + col] = f2bf(acc[ct][r]);
    }
  }
}

// ---------- attention coefficient dots ----------
__global__ __launch_bounds__(256) void alpha1_kernel(const unsigned short* __restrict__ xpb,
                                                     const float* __restrict__ asv, const float* __restrict__ adv,
                                                     float* __restrict__ as1, float* __restrict__ ad1){
  int node = blockIdx.x*4 + (threadIdx.x>>6);
  int l = threadIdx.x & 63;
  if(node >= N_NODES) return;
  float x0 = bf2f(xpb[(size_t)node*128 + l]);
  float x1 = bf2f(xpb[(size_t)node*128 + 64 + l]);
  float s0 = x0*asv[l], s1 = x1*asv[64+l];
  float d0 = x0*adv[l], d1 = x1*adv[64+l];
  for(int off=32; off; off>>=1){
    s0 += __shfl_xor(s0, off); s1 += __shfl_xor(s1, off);
    d0 += __shfl_xor(d0, off); d1 += __shfl_xor(d1, off);
  }
  if(l == 0){ as1[node*2]=s0; as1[node*2+1]=s1; ad1[node*2]=d0; ad1[node*2+1]=d1; }
}

__global__ __launch_bounds__(256) void alpha2_kernel(const unsigned short* __restrict__ xpb2,
                                                     const float* __restrict__ asmu, const float* __restrict__ admu,
                                                     const float* __restrict__ asst, const float* __restrict__ adst,
                                                     float* __restrict__ as2, float* __restrict__ ad2){
  int node = blockIdx.x*4 + (threadIdx.x>>6);
  int l = threadIdx.x & 63;
  if(node >= N_NODES) return;
  int half = l >> 5, c = l & 31;
  float v = bf2f(xpb2[(size_t)node*64 + l]);
  float sp = v * (half ? asst[c] : asmu[c]);
  float dp = v * (half ? adst[c] : admu[c]);
  for(int off=16; off; off>>=1){ sp += __shfl_xor(sp, off); dp += __shfl_xor(dp, off); }
  if(c == 0){ as2[node*2+half] = sp; ad2[node*2+half] = dp; }
}

// ---------- per-edge softmax weights ----------
__global__ __launch_bounds__(256) void wcalc_kernel(const int2* __restrict__ epair,
                                                    const float* __restrict__ asv, const float* __restrict__ adv,
                                                    float2* __restrict__ wbuf){
  int i = blockIdx.x*256 + threadIdx.x;
  if(i >= ET) return;
  int2 e = epair[i];
  float2 a = ((const float2*)asv)[e.x];
  float2 b = ((const float2*)adv)[e.y];
  float2 w;
  w.x = __expf(lrelu(a.x + b.x));
  w.y = __expf(lrelu(a.y + b.y));
  wbuf[i] = w;
}

// ---------- edge aggregation, layer 1 (bf16 gathers; scalarized unroll-16) ----------
__global__ __launch_bounds__(256) void agg1_kernel(const int* __restrict__ rowptr, const int2* __restrict__ epair,
                                                   const float2* __restrict__ wbuf, const unsigned int* __restrict__ xb,
                                                   const float* __restrict__ b1, unsigned int* __restrict__ hb){
  int node = blockIdx.x*4 + (threadIdx.x>>6);
  int l = threadIdx.x & 63;
  if(node >= N_NODES) return;
  int beg = rowptr[node], end = rowptr[node+1];
  float accx = 0.f, accy = 0.f, s0 = 0.f, s1 = 0.f;
  int n = end - beg;
  int i = beg;

#define A1_E(j)  int e##j = epair[i+j].x;
#define A1_W(j)  float2 w##j = wbuf[i+j];
#define A1_U(j)  unsigned int u##j = xb[(size_t)e##j*64 + l];
#define A1_ACC(j) { s0 += w##j.x; s1 += w##j.y; \
                    float vv = (l < 32) ? w##j.x : w##j.y; \
                    accx += vv * __uint_as_float(u##j<<16); \
                    accy += vv * __uint_as_float(u##j&0xffff0000u); }

  int end16 = beg + (n & ~15);
  for(; i < end16; i += 16){
    A1_E(0) A1_E(1) A1_E(2) A1_E(3) A1_E(4) A1_E(5) A1_E(6) A1_E(7)
    A1_E(8) A1_E(9) A1_E(10) A1_E(11) A1_E(12) A1_E(13) A1_E(14) A1_E(15)
    A1_W(0) A1_W(1) A1_W(2) A1_W(3) A1_W(4) A1_W(5) A1_W(6) A1_W(7)
    A1_W(8) A1_W(9) A1_W(10) A1_W(11) A1_W(12) A1_W(13) A1_W(14) A1_W(15)
    A1_U(0) A1_U(1) A1_U(2) A1_U(3) A1_U(4) A1_U(5) A1_U(6) A1_U(7)
    A1_U(8) A1_U(9) A1_U(10) A1_U(11) A1_U(12) A1_U(13) A1_U(14) A1_U(15)
    A1_ACC(0) A1_ACC(1) A1_ACC(2) A1_ACC(3) A1_ACC(4) A1_ACC(5) A1_ACC(6) A1_ACC(7)
    A1_ACC(8) A1_ACC(9) A1_ACC(10) A1_ACC(11) A1_ACC(12) A1_ACC(13) A1_ACC(14) A1_ACC(15)
  }
  int end8 = end16 + ((end - end16) & ~7);
  for(; i < end8; i += 8){
    A1_E(0) A1_E(1) A1_E(2) A1_E(3) A1_E(4) A1_E(5) A1_E(6) A1_E(7)
    A1_W(0) A1_W(1) A1_W(2) A1_W(3) A1_W(4) A1_W(5) A1_W(6) A1_W(7)
    A1_U(0) A1_U(1) A1_U(2) A1_U(3) A1_U(4) A1_U(5) A1_U(6) A1_U(7)
    A1_ACC(0) A1_ACC(1) A1_ACC(2) A1_ACC(3) A1_ACC(4) A1_ACC(5) A1_ACC(6) A1_ACC(7)
  }
  for(; i < end; i++){
    int s = epair[i].x;
    float2 w = wbuf[i];
    s0 += w.x; s1 += w.y;
    unsigned int u = xb[(size_t)s*64 + l];
    float ww = (l < 32) ? w.x : w.y;
    accx += ww * __uint_as_float(u<<16);
    accy += ww * __uint_as_float(u&0xffff0000u);
  }
  float sd = (l < 32) ? s0 : s1;
  float2 bb = ((const float2*)b1)[l];
  float rx = fmaxf(accx/sd + bb.x, 0.f);
  float ry = fmaxf(accy/sd + bb.y, 0.f);
  unsigned int hp = (unsigned int)f2bf(rx) | ((unsigned int)f2bf(ry) << 16);
  hb[(size_t)node*64 + l] = hp;
}

// ---------- edge aggregation, layer 2 (bf16 gathers; mu+std fused; unroll-16) ----------
__global__ __launch_bounds__(256) void agg2_kernel(const int* __restrict__ rowptr, const int2* __restrict__ epair,
                                                   const float2* __restrict__ wbuf, const unsigned short* __restrict__ xb2,
                                                   const float* __restrict__ bmu, const float* __restrict__ bst,
                                                   float* __restrict__ out){
  int node = blockIdx.x*4 + (threadIdx.x>>6);
  int l = threadIdx.x & 63;
  if(node >= N_NODES) return;
  int half = l >> 5, c = l & 31;
  int beg = rowptr[node], end = rowptr[node+1];
  float acc = 0.f, ssum = 0.f;
  int n = end - beg;
  int i = beg;

#define A2_E(j)  int e##j = epair[i+j].x;
#define A2_W(j)  float2 w##j = wbuf[i+j];
#define A2_X(j)  float x##j = bf2f(xb2[(size_t)e##j*64 + l]);
#define A2_ACC(j) { float vv = half ? w##j.y : w##j.x; ssum += vv; acc += vv * x##j; }

  int end16 = beg + (n & ~15);
  for(; i < end16; i += 16){
    A2_E(0) A2_E(1) A2_E(2) A2_E(3) A2_E(4) A2_E(5) A2_E(6) A2_E(7)
    A2_E(8) A2_E(9) A2_E(10) A2_E(11) A2_E(12) A2_E(13) A2_E(14) A2_E(15)
    A2_W(0) A2_W(1) A2_W(2) A2_W(3) A2_W(4) A2_W(5) A2_W(6) A2_W(7)
    A2_W(8) A2_W(9) A2_W(10) A2_W(11) A2_W(12) A2_W(13) A2_W(14) A2_W(15)
    A2_X(0) A2_X(1) A2_X(2) A2_X(3) A2_X(4) A2_X(5) A2_X(6) A2_X(7)
    A2_X(8) A2_X(9) A2_X(10) A2_X(11) A2_X(12) A2_X(13) A2_X(14) A2_X(15)
    A2_ACC(0) A2_ACC(1) A2_ACC(2) A2_ACC(3) A2_ACC(4) A2_ACC(5) A2_ACC(6) A2_ACC(7)
    A2_ACC(8) A2_ACC(9) A2_ACC(10) A2_ACC(11) A2_ACC(12) A2_ACC(13) A2_ACC(14) A2_ACC(15)
  }
  int end8 = end16 + ((end - end16) & ~7);
  for(; i < end8; i += 8){
    A2_E(0) A2_E(1) A2_E(2) A2_E(3) A2_E(4) A2_E(5) A2_E(6) A2_E(7)
    A2_W(0) A2_W(1) A2_W(2) A2_W(3) A2_W(4) A2_W(5) A2_W(6) A2_W(7)
    A2_X(0) A2_X(1) A2_X(2) A2_X(3) A2_X(4) A2_X(5) A2_X(6) A2_X(7)
    A2_ACC(0) A2_ACC(1) A2_ACC(2) A2_ACC(3) A2_ACC(4) A2_ACC(5) A2_ACC(6) A2_ACC(7)
  }
  for(; i < end; i++){
    int s = epair[i].x;
    float2 w = wbuf[i];
    float ww = half ? w.y : w.x;
    ssum += ww;
    acc += ww * bf2f(xb2[(size_t)s*64 + l]);
  }
  float r = acc/ssum + (half ? bst[c] : bmu[c]);
  out[(half ? (size_t)N_NODES*Z : 0) + (size_t)node*Z + c] = r;
}

extern "C" void kernel_launch(void* const* d_in, const int* in_sizes, int n_in,
                              void* d_out, int out_size, void* d_ws, size_t ws_size,
                              hipStream_t stream){
  const float* x    = (const float*)d_in[0];
  const int*   edges= (const int*)d_in[1];
  const float* W1   = (const float*)d_in[2];
  const float* as1v = (const float*)d_in[3];
  const float* ad1v = (const float*)d_in[4];
  const float* b1   = (const float*)d_in[5];
  const float* Wmu  = (const float*)d_in[6];
  const float* asmu = (const float*)d_in[7];
  const float* admu = (const float*)d_in[8];
  const float* bmu  = (const float*)d_in[9];
  const float* Wst  = (const float*)d_in[10];
  const float* asst = (const float*)d_in[11];
  const float* adst = (const float*)d_in[12];
  const float* bst  = (const float*)d_in[13];
  float* out = (float*)d_out;

  char* p = (char*)d_ws;
  auto alloc = [&](size_t bytes)->char*{ char* r = p; p += (bytes + 255) & ~size_t(255); return r; };
  int*   M      = (int*)  alloc((size_t)MTOT*4);
  int*   Mpos   = (int*)  alloc((size_t)MTOT*4);
  int*   bsumM  = (int*)  alloc((size_t)MBS*4);
  int*   bpreM  = (int*)  alloc((size_t)MBS*4);
  int2*  etmp   = (int2*) alloc((size_t)ET*8);
  int2*  epair  = (int2*) alloc((size_t)ET*8);
  int*   deg    = (int*)  alloc((size_t)N_NODES*4);
  int*   rowptr = (int*)  alloc((size_t)(N_NODES+1)*4);
  int*   bsum   = (int*)  alloc((size_t)NBS*4);
  int*   bpre   = (int*)  alloc((size_t)NBS*4);
  unsigned short* Wb1 = (unsigned short*)alloc((size_t)128*KD*2);
  unsigned short* Wb2 = (unsigned short*)alloc((size_t)64*KD*2);
  unsigned short* xpb1 = (unsigned short*)alloc((size_t)N_NODES*128*2);
  float* as1    = (float*)alloc((size_t)N_NODES*2*4);
  float* ad1    = (float*)alloc((size_t)N_NODES*2*4);
  unsigned short* hb = (unsigned short*)alloc((size_t)N_NODES*128*2);
  float2* wbuf  = (float2*)alloc((size_t)ET*8);
  float* as2    = (float*)alloc((size_t)N_NODES*2*4);
  float* ad2    = (float*)alloc((size_t)N_NODES*2*4);
  unsigned short* xpb2 = xpb1;                          // xpb1 dead after agg1

  bhistA_kernel  <<<NBLKA, 256, 0, stream>>>(edges, M);
  scanM1_kernel  <<<MBS, 256, 0, stream>>>(M, bsumM);
  scanM2_kernel  <<<1, 256, 0, stream>>>(bsumM, bpreM);
  scanM3_kernel  <<<MBS, 256, 0, stream>>>(M, bpreM, Mpos);
  bplaceA_kernel <<<NBLKA, 256, 0, stream>>>(edges, Mpos, etmp);
  bhist2_kernel  <<<NBUCK, 256, 0, stream>>>(Mpos, etmp, deg);
  scan1_kernel   <<<NBS, 256, 0, stream>>>(deg, bsum);
  scan2_kernel   <<<1, 64, 0, stream>>>(bsum, bpre);
  scan3_kernel   <<<NBS, 256, 0, stream>>>(deg, bpre, rowptr);
  bplace_kernel  <<<NBUCK, 256, 0, stream>>>(Mpos, etmp, rowptr, epair);

  wconv_kernel   <<<(128*KD + 255)/256, 256, 0, stream>>>(W1, Wmu, Wst, Wb1, Wb2);

  mmt_kernel<128,false><<<(N_NODES+63)/64, 256, 0, stream>>>(x, Wb1, xpb1);
  alpha1_kernel<<<(N_NODES+3)/4, 256, 0, stream>>>(xpb1, as1v, ad1v, as1, ad1);
  wcalc_kernel <<<(ET+255)/256, 256, 0, stream>>>(epair, as1, ad1, wbuf);
  agg1_kernel  <<<(N_NODES+3)/4, 256, 0, stream>>>(rowptr, epair, wbuf, (const unsigned int*)xpb1, b1, (unsigned int*)hb);

  mmt_kernel<64,true><<<(N_NODES+63)/64, 256, 0, stream>>>(hb, Wb2, xpb1);
  alpha2_kernel<<<(N_NODES+3)/4, 256, 0, stream>>>(xpb2, asmu, admu, asst, adst, as2, ad2);
  wcalc_kernel <<<(ET+255)/256, 256, 0, stream>>>(epair, as2, ad2, wbuf);
  agg2_kernel  <<<(N_NODES+3)/4, 256, 0, stream>>>(rowptr, epair, wbuf, xpb2, bmu, bst, out);
}

// Round 12
// 262.113 us; speedup vs baseline: 1.1543x; 1.1543x over previous
//
#include <hip/hip_runtime.h>
#include <math.h>

#define N_NODES 50000
#define N_EDGES 800000
#define ET (N_EDGES + N_NODES)   // 850000 incl. self-loops
#define KD 128
#define Z 32
#define SH 7
#define BW 128                              // nodes per bucket
#define NBUCK ((N_NODES + BW - 1) / BW)     // 391
#define CHUNK 2048
#define NBLKA ((ET + CHUNK - 1) / CHUNK)    // 416 chunks
#define MTOT (NBUCK * NBLKA)                // 162,656
#define MBS ((MTOT + 1023) / 1024)          // 159

typedef __attribute__((ext_vector_type(8))) short bf16x8;
typedef __attribute__((ext_vector_type(4))) float f32x4;

static __device__ __forceinline__ float lrelu(float x){ return x > 0.f ? x : 0.2f*x; }
static __device__ __forceinline__ float bf2f(unsigned int u16){ return __uint_as_float(u16 << 16); }
static __device__ __forceinline__ unsigned short f2bf(float f){
  unsigned int x = __float_as_uint(f);
  return (unsigned short)((x + 0x7fffu + ((x >> 16) & 1u)) >> 16);   // RNE
}

// ---------- CSR build: counting sort, NO global atomics ----------
__global__ __launch_bounds__(256) void bhistA_kernel(const int* __restrict__ edges, int* __restrict__ M){
  int k = blockIdx.x, t = threadIdx.x;
  __shared__ int cnt[NBUCK];
  for(int b = t; b < NBUCK; b += 256) cnt[b] = 0;
  __syncthreads();
  int base = k*CHUNK;
  int lim = min(base + CHUNK, ET);
  for(int i = base + t; i < lim; i += 256){
    int d = (i < N_EDGES) ? edges[N_EDGES + i] : (i - N_EDGES);
    atomicAdd(&cnt[d >> SH], 1);
  }
  __syncthreads();
  for(int b = t; b < NBUCK; b += 256) M[b*NBLKA + k] = cnt[b];
}

__global__ __launch_bounds__(256) void scanM1_kernel(const int* __restrict__ M, int* __restrict__ bsumM){
  int b = blockIdx.x, t = threadIdx.x;
  int base = b*1024 + t*4;
  int s = 0;
  #pragma unroll
  for(int i=0;i<4;i++){ int n = base+i; if(n < MTOT) s += M[n]; }
  for(int off=32; off; off>>=1) s += __shfl_xor(s, off);
  __shared__ int ws[4];
  if((t&63)==0) ws[t>>6] = s;
  __syncthreads();
  if(t==0) bsumM[b] = ws[0]+ws[1]+ws[2]+ws[3];
}

__global__ __launch_bounds__(256) void scanM2_kernel(const int* __restrict__ bsumM, int* __restrict__ bpreM){
  __shared__ int sm[256];
  int t = threadIdx.x;
  int v = (t < MBS) ? bsumM[t] : 0;
  sm[t] = v;
  __syncthreads();
  for(int off=1; off<256; off<<=1){
    int u = (t >= off) ? sm[t-off] : 0;
    __syncthreads();
    sm[t] += u;
    __syncthreads();
  }
  if(t < MBS) bpreM[t] = sm[t] - v;
}

__global__ __launch_bounds__(256) void scanM3_kernel(const int* __restrict__ M, const int* __restrict__ bpreM,
                                                     int* __restrict__ Mpos){
  int b = blockIdx.x, t = threadIdx.x;
  int lane = t & 63, wv = t >> 6;
  int base = b*1024 + t*4;
  int d[4]; int s = 0;
  #pragma unroll
  for(int i=0;i<4;i++){ int n = base+i; d[i] = (n < MTOT) ? M[n] : 0; s += d[i]; }
  int v = s;
  for(int off=1; off<64; off<<=1){
    int u = __shfl_up(v, off);
    if(lane >= off) v += u;
  }
  int texcl = v - s;
  __shared__ int wtot[4];
  if(lane == 63) wtot[wv] = v;
  __syncthreads();
  int woff = 0;
  for(int i=0;i<wv;i++) woff += wtot[i];
  int run = bpreM[b] + woff + texcl;
  #pragma unroll
  for(int i=0;i<4;i++){
    int n = base+i;
    if(n < MTOT){ Mpos[n] = run; run += d[i]; }
  }
}

__global__ __launch_bounds__(256) void bplaceA_kernel(const int* __restrict__ edges, const int* __restrict__ Mpos,
                                                      int2* __restrict__ etmp){
  int k = blockIdx.x, t = threadIdx.x;
  __shared__ int cur[NBUCK];
  for(int b = t; b < NBUCK; b += 256) cur[b] = Mpos[b*NBLKA + k];
  __syncthreads();
  int base = k*CHUNK;
  int lim = min(base + CHUNK, ET);
  for(int i = base + t; i < lim; i += 256){
    int s, d;
    if(i < N_EDGES){ s = edges[i]; d = edges[N_EDGES+i]; } else { s = d = i - N_EDGES; }
    int pos = atomicAdd(&cur[d >> SH], 1);
    etmp[pos] = make_int2(s, d);
  }
}

// fused: per-bucket node histogram + local scan -> rowptr + in-bucket place -> epair
__global__ __launch_bounds__(256) void bfin_kernel(const int* __restrict__ Mpos, const int2* __restrict__ etmp,
                                                   int* __restrict__ rowptr, int2* __restrict__ epair){
  int b = blockIdx.x, t = threadIdx.x;
  __shared__ int cnt[BW];
  __shared__ int pre[BW];
  __shared__ int lcur[BW];
  if(t < BW) cnt[t] = 0;
  __syncthreads();
  int beg = Mpos[b*NBLKA];
  int end = (b+1 < NBUCK) ? Mpos[(b+1)*NBLKA] : ET;
  for(int i = beg + t; i < end; i += 256) atomicAdd(&cnt[etmp[i].y & (BW-1)], 1);
  __syncthreads();
  if(t < BW) pre[t] = cnt[t];
  __syncthreads();
  for(int off=1; off<BW; off<<=1){
    int u = 0;
    if(t < BW && t >= off) u = pre[t-off];
    __syncthreads();
    if(t < BW) pre[t] += u;
    __syncthreads();
  }
  if(t < BW){
    int excl = pre[t] - cnt[t];
    int node = b*BW + t;
    if(node < N_NODES) rowptr[node] = beg + excl;
    lcur[t] = beg + excl;
  }
  if(b == 0 && t == 255) rowptr[N_NODES] = ET;
  __syncthreads();
  for(int i = beg + t; i < end; i += 256){
    int2 e = etmp[i];
    int pos = atomicAdd(&lcur[e.y & (BW-1)], 1);
    epair[pos] = e;
  }
}

// ---------- W -> bf16 converter ----------
__global__ __launch_bounds__(256) void wconv_kernel(const float* __restrict__ W1,
                                                    const float* __restrict__ Wmu, const float* __restrict__ Wst,
                                                    unsigned short* __restrict__ Wb1, unsigned short* __restrict__ Wb2){
  int i = blockIdx.x*256 + threadIdx.x;
  if(i < 128*KD) Wb1[i] = f2bf(W1[i]);
  if(i < 64*KD) Wb2[i] = f2bf(i < 32*KD ? Wmu[i] : Wst[i - 32*KD]);
}

// ---------- MFMA matmul layer1 (OC=128) + fused alpha1 ----------
__global__ __launch_bounds__(256) void mmt1_kernel(const float* __restrict__ X,
                                                   const unsigned short* __restrict__ Wb,
                                                   const float* __restrict__ asv, const float* __restrict__ adv,
                                                   unsigned short* __restrict__ outb,
                                                   float* __restrict__ as1, float* __restrict__ ad1){
  constexpr int OC = 128, CT = 8;
  int t = threadIdx.x;
  int w = t >> 6, L = t & 63;
  int col = L & 15, quad = L >> 4;
  int row0 = blockIdx.x*64 + w*16;
  int rA = row0 + col;
  if(rA >= N_NODES) rA = N_NODES-1;

  f32x4 acc[CT];
  #pragma unroll
  for(int ct=0;ct<CT;ct++) acc[ct] = (f32x4){0.f,0.f,0.f,0.f};

  #pragma unroll
  for(int kc=0;kc<4;kc++){
    int k0 = kc*32 + quad*8;
    const float* Xf = X + (size_t)rA*KD + k0;
    float4 p = *(const float4*)Xf;
    float4 q = *(const float4*)(Xf + 4);
    bf16x8 a;
    a[0] = (short)f2bf(p.x); a[1] = (short)f2bf(p.y);
    a[2] = (short)f2bf(p.z); a[3] = (short)f2bf(p.w);
    a[4] = (short)f2bf(q.x); a[5] = (short)f2bf(q.y);
    a[6] = (short)f2bf(q.z); a[7] = (short)f2bf(q.w);
    #pragma unroll
    for(int ct=0;ct<CT;ct++){
      bf16x8 b = *(const bf16x8*)(Wb + (size_t)(ct*16 + col)*KD + k0);
      acc[ct] = __builtin_amdgcn_mfma_f32_16x16x32_bf16(a, b, acc[ct], 0, 0, 0);
    }
  }

  float av[CT], dv[CT];
  #pragma unroll
  for(int ct=0;ct<CT;ct++){ av[ct] = asv[ct*16 + col]; dv[ct] = adv[ct*16 + col]; }

  #pragma unroll
  for(int r=0;r<4;r++){
    int row = row0 + quad*4 + r;
    #pragma unroll
    for(int ct=0;ct<CT;ct++)
      if(row < N_NODES) outb[(size_t)row*OC + ct*16 + col] = f2bf(acc[ct][r]);
    float s0 = acc[0][r]*av[0] + acc[1][r]*av[1] + acc[2][r]*av[2] + acc[3][r]*av[3];
    float s1 = acc[4][r]*av[4] + acc[5][r]*av[5] + acc[6][r]*av[6] + acc[7][r]*av[7];
    float d0 = acc[0][r]*dv[0] + acc[1][r]*dv[1] + acc[2][r]*dv[2] + acc[3][r]*dv[3];
    float d1 = acc[4][r]*dv[4] + acc[5][r]*dv[5] + acc[6][r]*dv[6] + acc[7][r]*dv[7];
    #pragma unroll
    for(int off=1; off<16; off<<=1){
      s0 += __shfl_xor(s0, off); s1 += __shfl_xor(s1, off);
      d0 += __shfl_xor(d0, off); d1 += __shfl_xor(d1, off);
    }
    if(col == 0 && row < N_NODES){
      as1[row*2] = s0; as1[row*2+1] = s1;
      ad1[row*2] = d0; ad1[row*2+1] = d1;
    }
  }
}

// ---------- MFMA matmul layer2 (OC=64, bf16 X) + fused alpha2 ----------
__global__ __launch_bounds__(256) void mmt2_kernel(const unsigned short* __restrict__ Xb,
                                                   const unsigned short* __restrict__ Wb,
                                                   const float* __restrict__ asmu, const float* __restrict__ admu,
                                                   const float* __restrict__ asst, const float* __restrict__ adst,
                                                   unsigned short* __restrict__ outb,
                                                   float* __restrict__ as2, float* __restrict__ ad2){
  constexpr int OC = 64, CT = 4;
  int t = threadIdx.x;
  int w = t >> 6, L = t & 63;
  int col = L & 15, quad = L >> 4;
  int row0 = blockIdx.x*64 + w*16;
  int rA = row0 + col;
  if(rA >= N_NODES) rA = N_NODES-1;

  f32x4 acc[CT];
  #pragma unroll
  for(int ct=0;ct<CT;ct++) acc[ct] = (f32x4){0.f,0.f,0.f,0.f};

  #pragma unroll
  for(int kc=0;kc<4;kc++){
    int k0 = kc*32 + quad*8;
    bf16x8 a = *(const bf16x8*)(Xb + (size_t)rA*KD + k0);
    #pragma unroll
    for(int ct=0;ct<CT;ct++){
      bf16x8 b = *(const bf16x8*)(Wb + (size_t)(ct*16 + col)*KD + k0);
      acc[ct] = __builtin_amdgcn_mfma_f32_16x16x32_bf16(a, b, acc[ct], 0, 0, 0);
    }
  }

  float av[CT], dv[CT];
  #pragma unroll
  for(int ct=0;ct<CT;ct++){
    av[ct] = (ct < 2) ? asmu[ct*16 + col] : asst[(ct-2)*16 + col];
    dv[ct] = (ct < 2) ? admu[ct*16 + col] : adst[(ct-2)*16 + col];
  }

  #pragma unroll
  for(int r=0;r<4;r++){
    int row = row0 + quad*4 + r;
    #pragma unroll
    for(int ct=0;ct<CT;ct++)
      if(row < N_NODES) outb[(size_t)row*OC + ct*16 + col] = f2bf(acc[ct][r]);
    float smu = acc[0][r]*av[0] + acc[1][r]*av[1];
    float sst = acc[2][r]*av[2] + acc[3][r]*av[3];
    float dmu = acc[0][r]*dv[0] + acc[1][r]*dv[1];
    float dst = acc[2][r]*dv[2] + acc[3][r]*dv[3];
    #pragma unroll
    for(int off=1; off<16; off<<=1){
      smu += __shfl_xor(smu, off); sst += __shfl_xor(sst, off);
      dmu += __shfl_xor(dmu, off); dst += __shfl_xor(dst, off);
    }
    if(col == 0 && row < N_NODES){
      as2[row*2] = smu; as2[row*2+1] = sst;
      ad2[row*2] = dmu; ad2[row*2+1] = dst;
    }
  }
}

// ---------- per-edge softmax weights ----------
__global__ __launch_bounds__(256) void wcalc_kernel(const int2* __restrict__ epair,
                                                    const float* __restrict__ asv, const float* __restrict__ adv,
                                                    float2* __restrict__ wbuf){
  int i = blockIdx.x*256 + threadIdx.x;
  if(i >= ET) return;
  int2 e = epair[i];
  float2 a = ((const float2*)asv)[e.x];
  float2 b = ((const float2*)adv)[e.y];
  float2 w;
  w.x = __expf(lrelu(a.x + b.x));
  w.y = __expf(lrelu(a.y + b.y));
  wbuf[i] = w;
}

// ---------- edge aggregation, layer 1 (bf16 gathers; scalarized unroll-8) ----------
__global__ __launch_bounds__(256) void agg1_kernel(const int* __restrict__ rowptr, const int2* __restrict__ epair,
                                                   const float2* __restrict__ wbuf, const unsigned int* __restrict__ xb,
                                                   const float* __restrict__ b1, unsigned int* __restrict__ hb){
  int node = blockIdx.x*4 + (threadIdx.x>>6);
  int l = threadIdx.x & 63;
  if(node >= N_NODES) return;
  int beg = rowptr[node], end = rowptr[node+1];
  float accx = 0.f, accy = 0.f, s0 = 0.f, s1 = 0.f;
  int n = end - beg;
  int nq = n & ~7;
  for(int q = 0; q < nq; q += 8){
    int e0 = epair[beg+q+0].x, e1 = epair[beg+q+1].x, e2 = epair[beg+q+2].x, e3 = epair[beg+q+3].x;
    int e4 = epair[beg+q+4].x, e5 = epair[beg+q+5].x, e6 = epair[beg+q+6].x, e7 = epair[beg+q+7].x;
    float2 w0 = wbuf[beg+q+0], w1 = wbuf[beg+q+1], w2 = wbuf[beg+q+2], w3 = wbuf[beg+q+3];
    float2 w4 = wbuf[beg+q+4], w5 = wbuf[beg+q+5], w6 = wbuf[beg+q+6], w7 = wbuf[beg+q+7];
    unsigned int u0 = xb[(size_t)e0*64 + l], u1 = xb[(size_t)e1*64 + l];
    unsigned int u2 = xb[(size_t)e2*64 + l], u3 = xb[(size_t)e3*64 + l];
    unsigned int u4 = xb[(size_t)e4*64 + l], u5 = xb[(size_t)e5*64 + l];
    unsigned int u6 = xb[(size_t)e6*64 + l], u7 = xb[(size_t)e7*64 + l];
    s0 += w0.x + w1.x + w2.x + w3.x + w4.x + w5.x + w6.x + w7.x;
    s1 += w0.y + w1.y + w2.y + w3.y + w4.y + w5.y + w6.y + w7.y;
    float v0 = (l < 32) ? w0.x : w0.y;
    float v1 = (l < 32) ? w1.x : w1.y;
    float v2 = (l < 32) ? w2.x : w2.y;
    float v3 = (l < 32) ? w3.x : w3.y;
    float v4 = (l < 32) ? w4.x : w4.y;
    float v5 = (l < 32) ? w5.x : w5.y;
    float v6 = (l < 32) ? w6.x : w6.y;
    float v7 = (l < 32) ? w7.x : w7.y;
    accx += v0*__uint_as_float(u0<<16) + v1*__uint_as_float(u1<<16)
          + v2*__uint_as_float(u2<<16) + v3*__uint_as_float(u3<<16)
          + v4*__uint_as_float(u4<<16) + v5*__uint_as_float(u5<<16)
          + v6*__uint_as_float(u6<<16) + v7*__uint_as_float(u7<<16);
    accy += v0*__uint_as_float(u0&0xffff0000u) + v1*__uint_as_float(u1&0xffff0000u)
          + v2*__uint_as_float(u2&0xffff0000u) + v3*__uint_as_float(u3&0xffff0000u)
          + v4*__uint_as_float(u4&0xffff0000u) + v5*__uint_as_float(u5&0xffff0000u)
          + v6*__uint_as_float(u6&0xffff0000u) + v7*__uint_as_float(u7&0xffff0000u);
  }
  for(int i = beg + nq; i < end; i++){
    int s = epair[i].x;
    float2 w = wbuf[i];
    s0 += w.x; s1 += w.y;
    unsigned int u = xb[(size_t)s*64 + l];
    float ww = (l < 32) ? w.x : w.y;
    accx += ww * __uint_as_float(u<<16);
    accy += ww * __uint_as_float(u&0xffff0000u);
  }
  float sd = (l < 32) ? s0 : s1;
  float2 bb = ((const float2*)b1)[l];
  float rx = fmaxf(accx/sd + bb.x, 0.f);
  float ry = fmaxf(accy/sd + bb.y, 0.f);
  unsigned int hp = (unsigned int)f2bf(rx) | ((unsigned int)f2bf(ry) << 16);
  hb[(size_t)node*64 + l] = hp;
}

// ---------- edge aggregation, layer 2 (bf16 gathers; mu+std fused; unroll-8) ----------
__global__ __launch_bounds__(256) void agg2_kernel(const int* __restrict__ rowptr, const int2* __restrict__ epair,
                                                   const float2* __restrict__ wbuf, const unsigned short* __restrict__ xb2,
                                                   const float* __restrict__ bmu, const float* __restrict__ bst,
                                                   float* __restrict__ out){
  int node = blockIdx.x*4 + (threadIdx.x>>6);
  int l = threadIdx.x & 63;
  if(node >= N_NODES) return;
  int half = l >> 5, c = l & 31;
  int beg = rowptr[node], end = rowptr[node+1];
  float acc = 0.f, ssum = 0.f;
  int n = end - beg;
  int nq = n & ~7;
  for(int q = 0; q < nq; q += 8){
    int e0 = epair[beg+q+0].x, e1 = epair[beg+q+1].x, e2 = epair[beg+q+2].x, e3 = epair[beg+q+3].x;
    int e4 = epair[beg+q+4].x, e5 = epair[beg+q+5].x, e6 = epair[beg+q+6].x, e7 = epair[beg+q+7].x;
    float2 w0 = wbuf[beg+q+0], w1 = wbuf[beg+q+1], w2 = wbuf[beg+q+2], w3 = wbuf[beg+q+3];
    float2 w4 = wbuf[beg+q+4], w5 = wbuf[beg+q+5], w6 = wbuf[beg+q+6], w7 = wbuf[beg+q+7];
    float x0 = bf2f(xb2[(size_t)e0*64 + l]), x1 = bf2f(xb2[(size_t)e1*64 + l]);
    float x2 = bf2f(xb2[(size_t)e2*64 + l]), x3 = bf2f(xb2[(size_t)e3*64 + l]);
    float x4 = bf2f(xb2[(size_t)e4*64 + l]), x5 = bf2f(xb2[(size_t)e5*64 + l]);
    float x6 = bf2f(xb2[(size_t)e6*64 + l]), x7 = bf2f(xb2[(size_t)e7*64 + l]);
    float v0 = half ? w0.y : w0.x;
    float v1 = half ? w1.y : w1.x;
    float v2 = half ? w2.y : w2.x;
    float v3 = half ? w3.y : w3.x;
    float v4 = half ? w4.y : w4.x;
    float v5 = half ? w5.y : w5.x;
    float v6 = half ? w6.y : w6.x;
    float v7 = half ? w7.y : w7.x;
    ssum += v0 + v1 + v2 + v3 + v4 + v5 + v6 + v7;
    acc  += v0*x0 + v1*x1 + v2*x2 + v3*x3 + v4*x4 + v5*x5 + v6*x6 + v7*x7;
  }
  for(int i = beg + nq; i < end; i++){
    int s = epair[i].x;
    float2 w = wbuf[i];
    float ww = half ? w.y : w.x;
    ssum += ww;
    acc += ww * bf2f(xb2[(size_t)s*64 + l]);
  }
  float r = acc/ssum + (half ? bst[c] : bmu[c]);
  out[(half ? (size_t)N_NODES*Z : 0) + (size_t)node*Z + c] = r;
}

extern "C" void kernel_launch(void* const* d_in, const int* in_sizes, int n_in,
                              void* d_out, int out_size, void* d_ws, size_t ws_size,
                              hipStream_t stream){
  const float* x    = (const float*)d_in[0];
  const int*   edges= (const int*)d_in[1];
  const float* W1   = (const float*)d_in[2];
  const float* as1v = (const float*)d_in[3];
  const float* ad1v = (const float*)d_in[4];
  const float* b1   = (const float*)d_in[5];
  const float* Wmu  = (const float*)d_in[6];
  const float* asmu = (const float*)d_in[7];
  const float* admu = (const float*)d_in[8];
  const float* bmu  = (const float*)d_in[9];
  const float* Wst  = (const float*)d_in[10];
  const float* asst = (const float*)d_in[11];
  const float* adst = (const float*)d_in[12];
  const float* bst  = (const float*)d_in[13];
  float* out = (float*)d_out;

  char* p = (char*)d_ws;
  auto alloc = [&](size_t bytes)->char*{ char* r = p; p += (bytes + 255) & ~size_t(255); return r; };
  int*   M      = (int*)  alloc((size_t)MTOT*4);
  int*   Mpos   = (int*)  alloc((size_t)MTOT*4);
  int*   bsumM  = (int*)  alloc((size_t)MBS*4);
  int*   bpreM  = (int*)  alloc((size_t)MBS*4);
  int2*  etmp   = (int2*) alloc((size_t)ET*8);
  int2*  epair  = (int2*) alloc((size_t)ET*8);
  int*   rowptr = (int*)  alloc((size_t)(N_NODES+1)*4);
  unsigned short* Wb1 = (unsigned short*)alloc((size_t)128*KD*2);
  unsigned short* Wb2 = (unsigned short*)alloc((size_t)64*KD*2);
  unsigned short* xpb1 = (unsigned short*)alloc((size_t)N_NODES*128*2);
  float* as1    = (float*)alloc((size_t)N_NODES*2*4);
  float* ad1    = (float*)alloc((size_t)N_NODES*2*4);
  unsigned short* hb = (unsigned short*)alloc((size_t)N_NODES*128*2);
  float2* wbuf  = (float2*)alloc((size_t)ET*8);
  float* as2    = (float*)alloc((size_t)N_NODES*2*4);
  float* ad2    = (float*)alloc((size_t)N_NODES*2*4);
  unsigned short* xpb2 = xpb1;                          // xpb1 dead after agg1

  bhistA_kernel  <<<NBLKA, 256, 0, stream>>>(edges, M);
  scanM1_kernel  <<<MBS, 256, 0, stream>>>(M, bsumM);
  scanM2_kernel  <<<1, 256, 0, stream>>>(bsumM, bpreM);
  scanM3_kernel  <<<MBS, 256, 0, stream>>>(M, bpreM, Mpos);
  bplaceA_kernel <<<NBLKA, 256, 0, stream>>>(edges, Mpos, etmp);
  bfin_kernel    <<<NBUCK, 256, 0, stream>>>(Mpos, etmp, rowptr, epair);

  wconv_kernel   <<<(128*KD + 255)/256, 256, 0, stream>>>(W1, Wmu, Wst, Wb1, Wb2);

  mmt1_kernel <<<(N_NODES+63)/64, 256, 0, stream>>>(x, Wb1, as1v, ad1v, xpb1, as1, ad1);
  wcalc_kernel<<<(ET+255)/256, 256, 0, stream>>>(epair, as1, ad1, wbuf);
  agg1_kernel <<<(N_NODES+3)/4, 256, 0, stream>>>(rowptr, epair, wbuf, (const unsigned int*)xpb1, b1, (unsigned int*)hb);

  mmt2_kernel <<<(N_NODES+63)/64, 256, 0, stream>>>(hb, Wb2, asmu, admu, asst, adst, xpb1, as2, ad2);
  wcalc_kernel<<<(ET+255)/256, 256, 0, stream>>>(epair, as2, ad2, wbuf);
  agg2_kernel <<<(N_NODES+3)/4, 256, 0, stream>>>(rowptr, epair, wbuf, xpb2, bmu, bst, out);
}

// Round 13
// 250.544 us; speedup vs baseline: 1.2076x; 1.0462x over previous
//
#include <hip/hip_runtime.h>
#include <math.h>

#define N_NODES 50000
#define N_EDGES 800000
#define ET (N_EDGES + N_NODES)   // 850000 incl. self-loops
#define KD 128
#define Z 32
#define SH 7
#define BW 128                              // nodes per bucket
#define NBUCK ((N_NODES + BW - 1) / BW)     // 391
#define CHUNK 2048
#define NBLKA ((ET + CHUNK - 1) / CHUNK)    // 416 chunks
#define MTOT (NBUCK * NBLKA)                // 162,656
#define MBS ((MTOT + 1023) / 1024)          // 159

typedef __attribute__((ext_vector_type(8))) short bf16x8;
typedef __attribute__((ext_vector_type(4))) float f32x4;

static __device__ __forceinline__ float lrelu(float x){ return x > 0.f ? x : 0.2f*x; }
static __device__ __forceinline__ float bf2f(unsigned int u16){ return __uint_as_float(u16 << 16); }
static __device__ __forceinline__ float lof(unsigned int u){ return __uint_as_float(u << 16); }
static __device__ __forceinline__ float hif(unsigned int u){ return __uint_as_float(u & 0xffff0000u); }
static __device__ __forceinline__ unsigned short f2bf(float f){
  unsigned int x = __float_as_uint(f);
  return (unsigned short)((x + 0x7fffu + ((x >> 16) & 1u)) >> 16);   // RNE
}

// ---------- CSR build: counting sort, NO global atomics ----------
__global__ __launch_bounds__(256) void bhistA_kernel(const int* __restrict__ edges, int* __restrict__ M){
  int k = blockIdx.x, t = threadIdx.x;
  __shared__ int cnt[NBUCK];
  for(int b = t; b < NBUCK; b += 256) cnt[b] = 0;
  __syncthreads();
  int base = k*CHUNK;
  int lim = min(base + CHUNK, ET);
  for(int i = base + t; i < lim; i += 256){
    int d = (i < N_EDGES) ? edges[N_EDGES + i] : (i - N_EDGES);
    atomicAdd(&cnt[d >> SH], 1);
  }
  __syncthreads();
  for(int b = t; b < NBUCK; b += 256) M[b*NBLKA + k] = cnt[b];
}

__global__ __launch_bounds__(256) void scanM1_kernel(const int* __restrict__ M, int* __restrict__ bsumM){
  int b = blockIdx.x, t = threadIdx.x;
  int base = b*1024 + t*4;
  int s = 0;
  #pragma unroll
  for(int i=0;i<4;i++){ int n = base+i; if(n < MTOT) s += M[n]; }
  for(int off=32; off; off>>=1) s += __shfl_xor(s, off);
  __shared__ int ws[4];
  if((t&63)==0) ws[t>>6] = s;
  __syncthreads();
  if(t==0) bsumM[b] = ws[0]+ws[1]+ws[2]+ws[3];
}

__global__ __launch_bounds__(256) void scanM2_kernel(const int* __restrict__ bsumM, int* __restrict__ bpreM){
  __shared__ int sm[256];
  int t = threadIdx.x;
  int v = (t < MBS) ? bsumM[t] : 0;
  sm[t] = v;
  __syncthreads();
  for(int off=1; off<256; off<<=1){
    int u = (t >= off) ? sm[t-off] : 0;
    __syncthreads();
    sm[t] += u;
    __syncthreads();
  }
  if(t < MBS) bpreM[t] = sm[t] - v;
}

__global__ __launch_bounds__(256) void scanM3_kernel(const int* __restrict__ M, const int* __restrict__ bpreM,
                                                     int* __restrict__ Mpos){
  int b = blockIdx.x, t = threadIdx.x;
  int lane = t & 63, wv = t >> 6;
  int base = b*1024 + t*4;
  int d[4]; int s = 0;
  #pragma unroll
  for(int i=0;i<4;i++){ int n = base+i; d[i] = (n < MTOT) ? M[n] : 0; s += d[i]; }
  int v = s;
  for(int off=1; off<64; off<<=1){
    int u = __shfl_up(v, off);
    if(lane >= off) v += u;
  }
  int texcl = v - s;
  __shared__ int wtot[4];
  if(lane == 63) wtot[wv] = v;
  __syncthreads();
  int woff = 0;
  for(int i=0;i<wv;i++) woff += wtot[i];
  int run = bpreM[b] + woff + texcl;
  #pragma unroll
  for(int i=0;i<4;i++){
    int n = base+i;
    if(n < MTOT){ Mpos[n] = run; run += d[i]; }
  }
}

__global__ __launch_bounds__(256) void bplaceA_kernel(const int* __restrict__ edges, const int* __restrict__ Mpos,
                                                      int2* __restrict__ etmp){
  int k = blockIdx.x, t = threadIdx.x;
  __shared__ int cur[NBUCK];
  for(int b = t; b < NBUCK; b += 256) cur[b] = Mpos[b*NBLKA + k];
  __syncthreads();
  int base = k*CHUNK;
  int lim = min(base + CHUNK, ET);
  for(int i = base + t; i < lim; i += 256){
    int s, d;
    if(i < N_EDGES){ s = edges[i]; d = edges[N_EDGES+i]; } else { s = d = i - N_EDGES; }
    int pos = atomicAdd(&cur[d >> SH], 1);
    etmp[pos] = make_int2(s, d);
  }
}

// fused: per-bucket node histogram + local scan -> rowptr + in-bucket place -> epair
__global__ __launch_bounds__(256) void bfin_kernel(const int* __restrict__ Mpos, const int2* __restrict__ etmp,
                                                   int* __restrict__ rowptr, int2* __restrict__ epair){
  int b = blockIdx.x, t = threadIdx.x;
  __shared__ int cnt[BW];
  __shared__ int pre[BW];
  __shared__ int lcur[BW];
  if(t < BW) cnt[t] = 0;
  __syncthreads();
  int beg = Mpos[b*NBLKA];
  int end = (b+1 < NBUCK) ? Mpos[(b+1)*NBLKA] : ET;
  for(int i = beg + t; i < end; i += 256) atomicAdd(&cnt[etmp[i].y & (BW-1)], 1);
  __syncthreads();
  if(t < BW) pre[t] = cnt[t];
  __syncthreads();
  for(int off=1; off<BW; off<<=1){
    int u = 0;
    if(t < BW && t >= off) u = pre[t-off];
    __syncthreads();
    if(t < BW) pre[t] += u;
    __syncthreads();
  }
  if(t < BW){
    int excl = pre[t] - cnt[t];
    int node = b*BW + t;
    if(node < N_NODES) rowptr[node] = beg + excl;
    lcur[t] = beg + excl;
  }
  if(b == 0 && t == 255) rowptr[N_NODES] = ET;
  __syncthreads();
  for(int i = beg + t; i < end; i += 256){
    int2 e = etmp[i];
    int pos = atomicAdd(&lcur[e.y & (BW-1)], 1);
    epair[pos] = e;
  }
}

// ---------- W -> bf16 converter ----------
__global__ __launch_bounds__(256) void wconv_kernel(const float* __restrict__ W1,
                                                    const float* __restrict__ Wmu, const float* __restrict__ Wst,
                                                    unsigned short* __restrict__ Wb1, unsigned short* __restrict__ Wb2){
  int i = blockIdx.x*256 + threadIdx.x;
  if(i < 128*KD) Wb1[i] = f2bf(W1[i]);
  if(i < 64*KD) Wb2[i] = f2bf(i < 32*KD ? Wmu[i] : Wst[i - 32*KD]);
}

// ---------- MFMA matmul layer1 (OC=128) + fused alpha1 ----------
__global__ __launch_bounds__(256) void mmt1_kernel(const float* __restrict__ X,
                                                   const unsigned short* __restrict__ Wb,
                                                   const float* __restrict__ asv, const float* __restrict__ adv,
                                                   unsigned short* __restrict__ outb,
                                                   float* __restrict__ as1, float* __restrict__ ad1){
  constexpr int OC = 128, CT = 8;
  int t = threadIdx.x;
  int w = t >> 6, L = t & 63;
  int col = L & 15, quad = L >> 4;
  int row0 = blockIdx.x*64 + w*16;
  int rA = row0 + col;
  if(rA >= N_NODES) rA = N_NODES-1;

  f32x4 acc[CT];
  #pragma unroll
  for(int ct=0;ct<CT;ct++) acc[ct] = (f32x4){0.f,0.f,0.f,0.f};

  #pragma unroll
  for(int kc=0;kc<4;kc++){
    int k0 = kc*32 + quad*8;
    const float* Xf = X + (size_t)rA*KD + k0;
    float4 p = *(const float4*)Xf;
    float4 q = *(const float4*)(Xf + 4);
    bf16x8 a;
    a[0] = (short)f2bf(p.x); a[1] = (short)f2bf(p.y);
    a[2] = (short)f2bf(p.z); a[3] = (short)f2bf(p.w);
    a[4] = (short)f2bf(q.x); a[5] = (short)f2bf(q.y);
    a[6] = (short)f2bf(q.z); a[7] = (short)f2bf(q.w);
    #pragma unroll
    for(int ct=0;ct<CT;ct++){
      bf16x8 b = *(const bf16x8*)(Wb + (size_t)(ct*16 + col)*KD + k0);
      acc[ct] = __builtin_amdgcn_mfma_f32_16x16x32_bf16(a, b, acc[ct], 0, 0, 0);
    }
  }

  float av[CT], dv[CT];
  #pragma unroll
  for(int ct=0;ct<CT;ct++){ av[ct] = asv[ct*16 + col]; dv[ct] = adv[ct*16 + col]; }

  #pragma unroll
  for(int r=0;r<4;r++){
    int row = row0 + quad*4 + r;
    #pragma unroll
    for(int ct=0;ct<CT;ct++)
      if(row < N_NODES) outb[(size_t)row*OC + ct*16 + col] = f2bf(acc[ct][r]);
    float s0 = acc[0][r]*av[0] + acc[1][r]*av[1] + acc[2][r]*av[2] + acc[3][r]*av[3];
    float s1 = acc[4][r]*av[4] + acc[5][r]*av[5] + acc[6][r]*av[6] + acc[7][r]*av[7];
    float d0 = acc[0][r]*dv[0] + acc[1][r]*dv[1] + acc[2][r]*dv[2] + acc[3][r]*dv[3];
    float d1 = acc[4][r]*dv[4] + acc[5][r]*dv[5] + acc[6][r]*dv[6] + acc[7][r]*dv[7];
    #pragma unroll
    for(int off=1; off<16; off<<=1){
      s0 += __shfl_xor(s0, off); s1 += __shfl_xor(s1, off);
      d0 += __shfl_xor(d0, off); d1 += __shfl_xor(d1, off);
    }
    if(col == 0 && row < N_NODES){
      as1[row*2] = s0; as1[row*2+1] = s1;
      ad1[row*2] = d0; ad1[row*2+1] = d1;
    }
  }
}

// ---------- MFMA matmul layer2 (OC=64, bf16 X) + fused alpha2 ----------
__global__ __launch_bounds__(256) void mmt2_kernel(const unsigned short* __restrict__ Xb,
                                                   const unsigned short* __restrict__ Wb,
                                                   const float* __restrict__ asmu, const float* __restrict__ admu,
                                                   const float* __restrict__ asst, const float* __restrict__ adst,
                                                   unsigned short* __restrict__ outb,
                                                   float* __restrict__ as2, float* __restrict__ ad2){
  constexpr int OC = 64, CT = 4;
  int t = threadIdx.x;
  int w = t >> 6, L = t & 63;
  int col = L & 15, quad = L >> 4;
  int row0 = blockIdx.x*64 + w*16;
  int rA = row0 + col;
  if(rA >= N_NODES) rA = N_NODES-1;

  f32x4 acc[CT];
  #pragma unroll
  for(int ct=0;ct<CT;ct++) acc[ct] = (f32x4){0.f,0.f,0.f,0.f};

  #pragma unroll
  for(int kc=0;kc<4;kc++){
    int k0 = kc*32 + quad*8;
    bf16x8 a = *(const bf16x8*)(Xb + (size_t)rA*KD + k0);
    #pragma unroll
    for(int ct=0;ct<CT;ct++){
      bf16x8 b = *(const bf16x8*)(Wb + (size_t)(ct*16 + col)*KD + k0);
      acc[ct] = __builtin_amdgcn_mfma_f32_16x16x32_bf16(a, b, acc[ct], 0, 0, 0);
    }
  }

  float av[CT], dv[CT];
  #pragma unroll
  for(int ct=0;ct<CT;ct++){
    av[ct] = (ct < 2) ? asmu[ct*16 + col] : asst[(ct-2)*16 + col];
    dv[ct] = (ct < 2) ? admu[ct*16 + col] : adst[(ct-2)*16 + col];
  }

  #pragma unroll
  for(int r=0;r<4;r++){
    int row = row0 + quad*4 + r;
    #pragma unroll
    for(int ct=0;ct<CT;ct++)
      if(row < N_NODES) outb[(size_t)row*OC + ct*16 + col] = f2bf(acc[ct][r]);
    float smu = acc[0][r]*av[0] + acc[1][r]*av[1];
    float sst = acc[2][r]*av[2] + acc[3][r]*av[3];
    float dmu = acc[0][r]*dv[0] + acc[1][r]*dv[1];
    float dst = acc[2][r]*dv[2] + acc[3][r]*dv[3];
    #pragma unroll
    for(int off=1; off<16; off<<=1){
      smu += __shfl_xor(smu, off); sst += __shfl_xor(sst, off);
      dmu += __shfl_xor(dmu, off); dst += __shfl_xor(dst, off);
    }
    if(col == 0 && row < N_NODES){
      as2[row*2] = smu; as2[row*2+1] = sst;
      ad2[row*2] = dmu; ad2[row*2+1] = dst;
    }
  }
}

// ---------- per-edge softmax weights ----------
__global__ __launch_bounds__(256) void wcalc_kernel(const int2* __restrict__ epair,
                                                    const float* __restrict__ asv, const float* __restrict__ adv,
                                                    float2* __restrict__ wbuf){
  int i = blockIdx.x*256 + threadIdx.x;
  if(i >= ET) return;
  int2 e = epair[i];
  float2 a = ((const float2*)asv)[e.x];
  float2 b = ((const float2*)adv)[e.y];
  float2 w;
  w.x = __expf(lrelu(a.x + b.x));
  w.y = __expf(lrelu(a.y + b.y));
  wbuf[i] = w;
}

// ---------- agg layer 1: 2 edges/instr (half-wave per edge), uint2 gathers ----------
__global__ __launch_bounds__(256) void agg1_kernel(const int* __restrict__ rowptr, const int2* __restrict__ epair,
                                                   const float2* __restrict__ wbuf, const uint2* __restrict__ xb,
                                                   const float* __restrict__ b1, uint2* __restrict__ hb){
  int node = blockIdx.x*4 + (threadIdx.x>>6);
  int l = threadIdx.x & 63;
  if(node >= N_NODES) return;
  int half = l >> 5, c = l & 31;     // lane handles features 4c..4c+3 of its parity's edge
  int beg = rowptr[node], end = rowptr[node+1];
  int n = end - beg;
  float a0=0.f, a1=0.f, a2=0.f, a3=0.f, s0=0.f, s1=0.f;
  int npair = n >> 1;
  int mainp = npair & ~7;

#define G1(j) int e##j = epair[base + 2*j].x; float2 w##j = wbuf[base + 2*j];
#define U1(j) uint2 u##j = xb[(size_t)e##j*32 + c];
#define C1(j) { s0 += w##j.x; s1 += w##j.y; \
                float vv = (c < 16) ? w##j.x : w##j.y; \
                a0 += vv*lof(u##j.x); a1 += vv*hif(u##j.x); \
                a2 += vv*lof(u##j.y); a3 += vv*hif(u##j.y); }

  for(int pq = 0; pq < mainp; pq += 8){
    int base = beg + 2*pq + half;
    G1(0) G1(1) G1(2) G1(3) G1(4) G1(5) G1(6) G1(7)
    U1(0) U1(1) U1(2) U1(3) U1(4) U1(5) U1(6) U1(7)
    C1(0) C1(1) C1(2) C1(3) C1(4) C1(5) C1(6) C1(7)
  }
  for(int pq = mainp; pq < npair; pq++){
    int base = beg + 2*pq + half;
    G1(0) U1(0) C1(0)
  }
  if((n & 1) && half == 0){
    int idx = beg + n - 1;
    int e = epair[idx].x;
    float2 w = wbuf[idx];
    uint2 u = xb[(size_t)e*32 + c];
    s0 += w.x; s1 += w.y;
    float vv = (c < 16) ? w.x : w.y;
    a0 += vv*lof(u.x); a1 += vv*hif(u.x);
    a2 += vv*lof(u.y); a3 += vv*hif(u.y);
  }
#undef G1
#undef U1
#undef C1
  s0 += __shfl_xor(s0, 32); s1 += __shfl_xor(s1, 32);
  a0 += __shfl_xor(a0, 32); a1 += __shfl_xor(a1, 32);
  a2 += __shfl_xor(a2, 32); a3 += __shfl_xor(a3, 32);
  float sd = (c < 16) ? s0 : s1;
  float4 bb = *(const float4*)(b1 + 4*c);
  float r0 = fmaxf(a0/sd + bb.x, 0.f);
  float r1 = fmaxf(a1/sd + bb.y, 0.f);
  float r2 = fmaxf(a2/sd + bb.z, 0.f);
  float r3 = fmaxf(a3/sd + bb.w, 0.f);
  if(half == 0){
    uint2 o;
    o.x = (unsigned)f2bf(r0) | ((unsigned)f2bf(r1) << 16);
    o.y = (unsigned)f2bf(r2) | ((unsigned)f2bf(r3) << 16);
    hb[(size_t)node*32 + c] = o;
  }
}

// ---------- agg layer 2: 4 edges/instr (16 lanes per edge), uint2 gathers ----------
__global__ __launch_bounds__(256) void agg2_kernel(const int* __restrict__ rowptr, const int2* __restrict__ epair,
                                                   const float2* __restrict__ wbuf, const uint2* __restrict__ xb2,
                                                   const float* __restrict__ bmu, const float* __restrict__ bst,
                                                   float* __restrict__ out){
  int node = blockIdx.x*4 + (threadIdx.x>>6);
  int l = threadIdx.x & 63;
  if(node >= N_NODES) return;
  int g = l >> 4, c = l & 15;        // lane handles features 4c..4c+3 of edge (i+g)
  int beg = rowptr[node], end = rowptr[node+1];
  int n = end - beg;
  float a0=0.f, a1=0.f, a2=0.f, a3=0.f, smu=0.f, sst=0.f;
  int nquad = n >> 2;
  int mainq = nquad & ~3;

#define G2(j) int e##j = epair[base + 4*j].x; float2 w##j = wbuf[base + 4*j];
#define U2(j) uint2 u##j = xb2[(size_t)e##j*16 + c];
#define C2(j) { smu += w##j.x; sst += w##j.y; \
                float vv = (c < 8) ? w##j.x : w##j.y; \
                a0 += vv*lof(u##j.x); a1 += vv*hif(u##j.x); \
                a2 += vv*lof(u##j.y); a3 += vv*hif(u##j.y); }

  for(int qq = 0; qq < mainq; qq += 4){
    int base = beg + 4*qq + g;
    G2(0) G2(1) G2(2) G2(3)
    U2(0) U2(1) U2(2) U2(3)
    C2(0) C2(1) C2(2) C2(3)
  }
  for(int qq = mainq; qq < nquad; qq++){
    int base = beg + 4*qq + g;
    G2(0) U2(0) C2(0)
  }
  int tail = n & 3;
  if(g < tail){
    int idx = beg + 4*nquad + g;
    int e = epair[idx].x;
    float2 w = wbuf[idx];
    uint2 u = xb2[(size_t)e*16 + c];
    smu += w.x; sst += w.y;
    float vv = (c < 8) ? w.x : w.y;
    a0 += vv*lof(u.x); a1 += vv*hif(u.x);
    a2 += vv*lof(u.y); a3 += vv*hif(u.y);
  }
#undef G2
#undef U2
#undef C2
  #pragma unroll
  for(int off = 16; off < 64; off <<= 1){
    smu += __shfl_xor(smu, off); sst += __shfl_xor(sst, off);
    a0 += __shfl_xor(a0, off); a1 += __shfl_xor(a1, off);
    a2 += __shfl_xor(a2, off); a3 += __shfl_xor(a3, off);
  }
  float sd = (c < 8) ? smu : sst;
  float4 bb = (c < 8) ? *(const float4*)(bmu + 4*c) : *(const float4*)(bst + 4*(c-8));
  float4 r;
  r.x = a0/sd + bb.x;
  r.y = a1/sd + bb.y;
  r.z = a2/sd + bb.z;
  r.w = a3/sd + bb.w;
  if(g == 0){
    float* dst = (c < 8) ? (out + (size_t)node*Z + 4*c)
                         : (out + (size_t)N_NODES*Z + (size_t)node*Z + 4*(c-8));
    *(float4*)dst = r;
  }
}

extern "C" void kernel_launch(void* const* d_in, const int* in_sizes, int n_in,
                              void* d_out, int out_size, void* d_ws, size_t ws_size,
                              hipStream_t stream){
  const float* x    = (const float*)d_in[0];
  const int*   edges= (const int*)d_in[1];
  const float* W1   = (const float*)d_in[2];
  const float* as1v = (const float*)d_in[3];
  const float* ad1v = (const float*)d_in[4];
  const float* b1   = (const float*)d_in[5];
  const float* Wmu  = (const float*)d_in[6];
  const float* asmu = (const float*)d_in[7];
  const float* admu = (const float*)d_in[8];
  const float* bmu  = (const float*)d_in[9];
  const float* Wst  = (const float*)d_in[10];
  const float* asst = (const float*)d_in[11];
  const float* adst = (const float*)d_in[12];
  const float* bst  = (const float*)d_in[13];
  float* out = (float*)d_out;

  char* p = (char*)d_ws;
  auto alloc = [&](size_t bytes)->char*{ char* r = p; p += (bytes + 255) & ~size_t(255); return r; };
  int*   M      = (int*)  alloc((size_t)MTOT*4);
  int*   Mpos   = (int*)  alloc((size_t)MTOT*4);
  int*   bsumM  = (int*)  alloc((size_t)MBS*4);
  int*   bpreM  = (int*)  alloc((size_t)MBS*4);
  int2*  etmp   = (int2*) alloc((size_t)ET*8);
  int2*  epair  = (int2*) alloc((size_t)ET*8);
  int*   rowptr = (int*)  alloc((size_t)(N_NODES+1)*4);
  unsigned short* Wb1 = (unsigned short*)alloc((size_t)128*KD*2);
  unsigned short* Wb2 = (unsigned short*)alloc((size_t)64*KD*2);
  unsigned short* xpb1 = (unsigned short*)alloc((size_t)N_NODES*128*2);
  float* as1    = (float*)alloc((size_t)N_NODES*2*4);
  float* ad1    = (float*)alloc((size_t)N_NODES*2*4);
  unsigned short* hb = (unsigned short*)alloc((size_t)N_NODES*128*2);
  float2* wbuf  = (float2*)alloc((size_t)ET*8);
  float* as2    = (float*)alloc((size_t)N_NODES*2*4);
  float* ad2    = (float*)alloc((size_t)N_NODES*2*4);
  unsigned short* xpb2 = xpb1;                          // xpb1 dead after agg1

  bhistA_kernel  <<<NBLKA, 256, 0, stream>>>(edges, M);
  scanM1_kernel  <<<MBS, 256, 0, stream>>>(M, bsumM);
  scanM2_kernel  <<<1, 256, 0, stream>>>(bsumM, bpreM);
  scanM3_kernel  <<<MBS, 256, 0, stream>>>(M, bpreM, Mpos);
  bplaceA_kernel <<<NBLKA, 256, 0, stream>>>(edges, Mpos, etmp);
  bfin_kernel    <<<NBUCK, 256, 0, stream>>>(Mpos, etmp, rowptr, epair);

  wconv_kernel   <<<(128*KD + 255)/256, 256, 0, stream>>>(W1, Wmu, Wst, Wb1, Wb2);

  mmt1_kernel <<<(N_NODES+63)/64, 256, 0, stream>>>(x, Wb1, as1v, ad1v, xpb1, as1, ad1);
  wcalc_kernel<<<(ET+255)/256, 256, 0, stream>>>(epair, as1, ad1, wbuf);
  agg1_kernel <<<(N_NODES+3)/4, 256, 0, stream>>>(rowptr, epair, wbuf, (const uint2*)xpb1, b1, (uint2*)hb);

  mmt2_kernel <<<(N_NODES+63)/64, 256, 0, stream>>>(hb, Wb2, asmu, admu, asst, adst, xpb1, as2, ad2);
  wcalc_kernel<<<(ET+255)/256, 256, 0, stream>>>(epair, as2, ad2, wbuf);
  agg2_kernel <<<(N_NODES+3)/4, 256, 0, stream>>>(rowptr, epair, wbuf, (const uint2*)xpb2, bmu, bst, out);
}

// Round 14
// 249.416 us; speedup vs baseline: 1.2131x; 1.0045x over previous
//
#include <hip/hip_runtime.h>
#include <math.h>

#define N_NODES 50000
#define N_EDGES 800000
#define ET (N_EDGES + N_NODES)   // 850000 incl. self-loops
#define KD 128
#define Z 32
#define SH 7
#define BW 128                              // nodes per bucket
#define NBUCK ((N_NODES + BW - 1) / BW)     // 391
#define CHUNK 4096
#define NBLKA ((ET + CHUNK - 1) / CHUNK)    // 208 chunks
#define MTOT (NBUCK * NBLKA)                // 81,328
#define MBS ((MTOT + 1023) / 1024)          // 80

typedef __attribute__((ext_vector_type(8))) short bf16x8;
typedef __attribute__((ext_vector_type(4))) float f32x4;

static __device__ __forceinline__ float lrelu(float x){ return x > 0.f ? x : 0.2f*x; }
static __device__ __forceinline__ float bf2f(unsigned int u16){ return __uint_as_float(u16 << 16); }
static __device__ __forceinline__ float lof(unsigned int u){ return __uint_as_float(u << 16); }
static __device__ __forceinline__ float hif(unsigned int u){ return __uint_as_float(u & 0xffff0000u); }
static __device__ __forceinline__ unsigned short f2bf(float f){
  unsigned int x = __float_as_uint(f);
  return (unsigned short)((x + 0x7fffu + ((x >> 16) & 1u)) >> 16);   // RNE
}

// ---------- CSR build: counting sort, NO global atomics ----------
__global__ __launch_bounds__(256) void bhistA_kernel(const int* __restrict__ edges, int* __restrict__ M){
  int k = blockIdx.x, t = threadIdx.x;
  __shared__ int cnt[NBUCK];
  for(int b = t; b < NBUCK; b += 256) cnt[b] = 0;
  __syncthreads();
  int base = k*CHUNK;
  int lim = min(base + CHUNK, ET);
  for(int i = base + t; i < lim; i += 256){
    int d = (i < N_EDGES) ? edges[N_EDGES + i] : (i - N_EDGES);
    atomicAdd(&cnt[d >> SH], 1);
  }
  __syncthreads();
  for(int b = t; b < NBUCK; b += 256) M[b*NBLKA + k] = cnt[b];
}

__global__ __launch_bounds__(256) void scanM1_kernel(const int* __restrict__ M, int* __restrict__ bsumM){
  int b = blockIdx.x, t = threadIdx.x;
  int base = b*1024 + t*4;
  int s = 0;
  #pragma unroll
  for(int i=0;i<4;i++){ int n = base+i; if(n < MTOT) s += M[n]; }
  for(int off=32; off; off>>=1) s += __shfl_xor(s, off);
  __shared__ int ws[4];
  if((t&63)==0) ws[t>>6] = s;
  __syncthreads();
  if(t==0) bsumM[b] = ws[0]+ws[1]+ws[2]+ws[3];
}

__global__ __launch_bounds__(256) void scanM2_kernel(const int* __restrict__ bsumM, int* __restrict__ bpreM){
  __shared__ int sm[256];
  int t = threadIdx.x;
  int v = (t < MBS) ? bsumM[t] : 0;
  sm[t] = v;
  __syncthreads();
  for(int off=1; off<256; off<<=1){
    int u = (t >= off) ? sm[t-off] : 0;
    __syncthreads();
    sm[t] += u;
    __syncthreads();
  }
  if(t < MBS) bpreM[t] = sm[t] - v;
}

__global__ __launch_bounds__(256) void scanM3_kernel(const int* __restrict__ M, const int* __restrict__ bpreM,
                                                     int* __restrict__ Mpos){
  int b = blockIdx.x, t = threadIdx.x;
  int lane = t & 63, wv = t >> 6;
  int base = b*1024 + t*4;
  int d[4]; int s = 0;
  #pragma unroll
  for(int i=0;i<4;i++){ int n = base+i; d[i] = (n < MTOT) ? M[n] : 0; s += d[i]; }
  int v = s;
  for(int off=1; off<64; off<<=1){
    int u = __shfl_up(v, off);
    if(lane >= off) v += u;
  }
  int texcl = v - s;
  __shared__ int wtot[4];
  if(lane == 63) wtot[wv] = v;
  __syncthreads();
  int woff = 0;
  for(int i=0;i<wv;i++) woff += wtot[i];
  int run = bpreM[b] + woff + texcl;
  #pragma unroll
  for(int i=0;i<4;i++){
    int n = base+i;
    if(n < MTOT){ Mpos[n] = run; run += d[i]; }
  }
}

__global__ __launch_bounds__(256) void bplaceA_kernel(const int* __restrict__ edges, const int* __restrict__ Mpos,
                                                      int2* __restrict__ etmp){
  int k = blockIdx.x, t = threadIdx.x;
  __shared__ int cur[NBUCK];
  for(int b = t; b < NBUCK; b += 256) cur[b] = Mpos[b*NBLKA + k];
  __syncthreads();
  int base = k*CHUNK;
  int lim = min(base + CHUNK, ET);
  for(int i = base + t; i < lim; i += 256){
    int s, d;
    if(i < N_EDGES){ s = edges[i]; d = edges[N_EDGES+i]; } else { s = d = i - N_EDGES; }
    int pos = atomicAdd(&cur[d >> SH], 1);
    etmp[pos] = make_int2(s, d);
  }
}

// fused: per-bucket node histogram + local scan -> rowptr + in-bucket place -> esrc (int only)
__global__ __launch_bounds__(256) void bfin_kernel(const int* __restrict__ Mpos, const int2* __restrict__ etmp,
                                                   int* __restrict__ rowptr, int* __restrict__ esrc){
  int b = blockIdx.x, t = threadIdx.x;
  __shared__ int cnt[BW];
  __shared__ int pre[BW];
  __shared__ int lcur[BW];
  if(t < BW) cnt[t] = 0;
  __syncthreads();
  int beg = Mpos[b*NBLKA];
  int end = (b+1 < NBUCK) ? Mpos[(b+1)*NBLKA] : ET;
  for(int i = beg + t; i < end; i += 256) atomicAdd(&cnt[etmp[i].y & (BW-1)], 1);
  __syncthreads();
  if(t < BW) pre[t] = cnt[t];
  __syncthreads();
  for(int off=1; off<BW; off<<=1){
    int u = 0;
    if(t < BW && t >= off) u = pre[t-off];
    __syncthreads();
    if(t < BW) pre[t] += u;
    __syncthreads();
  }
  if(t < BW){
    int excl = pre[t] - cnt[t];
    int node = b*BW + t;
    if(node < N_NODES) rowptr[node] = beg + excl;
    lcur[t] = beg + excl;
  }
  if(b == 0 && t == 255) rowptr[N_NODES] = ET;
  __syncthreads();
  for(int i = beg + t; i < end; i += 256){
    int2 e = etmp[i];
    int pos = atomicAdd(&lcur[e.y & (BW-1)], 1);
    esrc[pos] = e.x;
  }
}

// ---------- W -> bf16 converter ----------
__global__ __launch_bounds__(256) void wconv_kernel(const float* __restrict__ W1,
                                                    const float* __restrict__ Wmu, const float* __restrict__ Wst,
                                                    unsigned short* __restrict__ Wb1, unsigned short* __restrict__ Wb2){
  int i = blockIdx.x*256 + threadIdx.x;
  if(i < 128*KD) Wb1[i] = f2bf(W1[i]);
  if(i < 64*KD) Wb2[i] = f2bf(i < 32*KD ? Wmu[i] : Wst[i - 32*KD]);
}

// ---------- MFMA matmul layer1 (OC=128) + fused alpha1 ----------
__global__ __launch_bounds__(256) void mmt1_kernel(const float* __restrict__ X,
                                                   const unsigned short* __restrict__ Wb,
                                                   const float* __restrict__ asv, const float* __restrict__ adv,
                                                   unsigned short* __restrict__ outb,
                                                   float* __restrict__ as1, float* __restrict__ ad1){
  constexpr int OC = 128, CT = 8;
  int t = threadIdx.x;
  int w = t >> 6, L = t & 63;
  int col = L & 15, quad = L >> 4;
  int row0 = blockIdx.x*64 + w*16;
  int rA = row0 + col;
  if(rA >= N_NODES) rA = N_NODES-1;

  f32x4 acc[CT];
  #pragma unroll
  for(int ct=0;ct<CT;ct++) acc[ct] = (f32x4){0.f,0.f,0.f,0.f};

  #pragma unroll
  for(int kc=0;kc<4;kc++){
    int k0 = kc*32 + quad*8;
    const float* Xf = X + (size_t)rA*KD + k0;
    float4 p = *(const float4*)Xf;
    float4 q = *(const float4*)(Xf + 4);
    bf16x8 a;
    a[0] = (short)f2bf(p.x); a[1] = (short)f2bf(p.y);
    a[2] = (short)f2bf(p.z); a[3] = (short)f2bf(p.w);
    a[4] = (short)f2bf(q.x); a[5] = (short)f2bf(q.y);
    a[6] = (short)f2bf(q.z); a[7] = (short)f2bf(q.w);
    #pragma unroll
    for(int ct=0;ct<CT;ct++){
      bf16x8 b = *(const bf16x8*)(Wb + (size_t)(ct*16 + col)*KD + k0);
      acc[ct] = __builtin_amdgcn_mfma_f32_16x16x32_bf16(a, b, acc[ct], 0, 0, 0);
    }
  }

  float av[CT], dv[CT];
  #pragma unroll
  for(int ct=0;ct<CT;ct++){ av[ct] = asv[ct*16 + col]; dv[ct] = adv[ct*16 + col]; }

  #pragma unroll
  for(int r=0;r<4;r++){
    int row = row0 + quad*4 + r;
    #pragma unroll
    for(int ct=0;ct<CT;ct++)
      if(row < N_NODES) outb[(size_t)row*OC + ct*16 + col] = f2bf(acc[ct][r]);
    float s0 = acc[0][r]*av[0] + acc[1][r]*av[1] + acc[2][r]*av[2] + acc[3][r]*av[3];
    float s1 = acc[4][r]*av[4] + acc[5][r]*av[5] + acc[6][r]*av[6] + acc[7][r]*av[7];
    float d0 = acc[0][r]*dv[0] + acc[1][r]*dv[1] + acc[2][r]*dv[2] + acc[3][r]*dv[3];
    float d1 = acc[4][r]*dv[4] + acc[5][r]*dv[5] + acc[6][r]*dv[6] + acc[7][r]*dv[7];
    #pragma unroll
    for(int off=1; off<16; off<<=1){
      s0 += __shfl_xor(s0, off); s1 += __shfl_xor(s1, off);
      d0 += __shfl_xor(d0, off); d1 += __shfl_xor(d1, off);
    }
    if(col == 0 && row < N_NODES){
      as1[row*2] = s0; as1[row*2+1] = s1;
      ad1[row*2] = d0; ad1[row*2+1] = d1;
    }
  }
}

// ---------- MFMA matmul layer2 (OC=64, bf16 X) + fused alpha2 ----------
__global__ __launch_bounds__(256) void mmt2_kernel(const unsigned short* __restrict__ Xb,
                                                   const unsigned short* __restrict__ Wb,
                                                   const float* __restrict__ asmu, const float* __restrict__ admu,
                                                   const float* __restrict__ asst, const float* __restrict__ adst,
                                                   unsigned short* __restrict__ outb,
                                                   float* __restrict__ as2, float* __restrict__ ad2){
  constexpr int OC = 64, CT = 4;
  int t = threadIdx.x;
  int w = t >> 6, L = t & 63;
  int col = L & 15, quad = L >> 4;
  int row0 = blockIdx.x*64 + w*16;
  int rA = row0 + col;
  if(rA >= N_NODES) rA = N_NODES-1;

  f32x4 acc[CT];
  #pragma unroll
  for(int ct=0;ct<CT;ct++) acc[ct] = (f32x4){0.f,0.f,0.f,0.f};

  #pragma unroll
  for(int kc=0;kc<4;kc++){
    int k0 = kc*32 + quad*8;
    bf16x8 a = *(const bf16x8*)(Xb + (size_t)rA*KD + k0);
    #pragma unroll
    for(int ct=0;ct<CT;ct++){
      bf16x8 b = *(const bf16x8*)(Wb + (size_t)(ct*16 + col)*KD + k0);
      acc[ct] = __builtin_amdgcn_mfma_f32_16x16x32_bf16(a, b, acc[ct], 0, 0, 0);
    }
  }

  float av[CT], dv[CT];
  #pragma unroll
  for(int ct=0;ct<CT;ct++){
    av[ct] = (ct < 2) ? asmu[ct*16 + col] : asst[(ct-2)*16 + col];
    dv[ct] = (ct < 2) ? admu[ct*16 + col] : adst[(ct-2)*16 + col];
  }

  #pragma unroll
  for(int r=0;r<4;r++){
    int row = row0 + quad*4 + r;
    #pragma unroll
    for(int ct=0;ct<CT;ct++)
      if(row < N_NODES) outb[(size_t)row*OC + ct*16 + col] = f2bf(acc[ct][r]);
    float smu = acc[0][r]*av[0] + acc[1][r]*av[1];
    float sst = acc[2][r]*av[2] + acc[3][r]*av[3];
    float dmu = acc[0][r]*dv[0] + acc[1][r]*dv[1];
    float dst = acc[2][r]*dv[2] + acc[3][r]*dv[3];
    #pragma unroll
    for(int off=1; off<16; off<<=1){
      smu += __shfl_xor(smu, off); sst += __shfl_xor(sst, off);
      dmu += __shfl_xor(dmu, off); dst += __shfl_xor(dst, off);
    }
    if(col == 0 && row < N_NODES){
      as2[row*2] = smu; as2[row*2+1] = sst;
      ad2[row*2] = dmu; ad2[row*2+1] = dst;
    }
  }
}

// ---------- agg layer 1: full-wave uint gathers, fused inline softmax weights ----------
__global__ __launch_bounds__(256) void agg1_kernel(const int* __restrict__ rowptr, const int* __restrict__ esrc,
                                                   const float* __restrict__ as1, const float* __restrict__ ad1,
                                                   const unsigned int* __restrict__ xb,
                                                   const float* __restrict__ b1, unsigned int* __restrict__ hb){
  int node = blockIdx.x*4 + (threadIdx.x>>6);
  int l = threadIdx.x & 63;
  if(node >= N_NODES) return;
  int beg = rowptr[node], end = rowptr[node+1];
  const float2* asp = (const float2*)as1;
  float2 adn = ((const float2*)ad1)[node];
  float accx = 0.f, accy = 0.f, s0 = 0.f, s1 = 0.f;
  int n = end - beg;
  int nq = n & ~7;

#define F1_E(j)  int e##j = esrc[i+j];
#define F1_A(j)  float2 a##j = asp[e##j];
#define F1_U(j)  unsigned int u##j = xb[(size_t)e##j*64 + l];
#define F1_C(j)  { float wx = __expf(lrelu(a##j.x + adn.x)); \
                   float wy = __expf(lrelu(a##j.y + adn.y)); \
                   s0 += wx; s1 += wy; \
                   float vv = (l < 32) ? wx : wy; \
                   accx += vv * lof(u##j); accy += vv * hif(u##j); }

  for(int i = beg; i < beg + nq; i += 8){
    F1_E(0) F1_E(1) F1_E(2) F1_E(3) F1_E(4) F1_E(5) F1_E(6) F1_E(7)
    F1_A(0) F1_A(1) F1_A(2) F1_A(3) F1_A(4) F1_A(5) F1_A(6) F1_A(7)
    F1_U(0) F1_U(1) F1_U(2) F1_U(3) F1_U(4) F1_U(5) F1_U(6) F1_U(7)
    F1_C(0) F1_C(1) F1_C(2) F1_C(3) F1_C(4) F1_C(5) F1_C(6) F1_C(7)
  }
  for(int i = beg + nq; i < end; i++){
    F1_E(0) F1_A(0) F1_U(0) F1_C(0)
  }
#undef F1_E
#undef F1_A
#undef F1_U
#undef F1_C
  float sd = (l < 32) ? s0 : s1;
  float2 bb = ((const float2*)b1)[l];
  float rx = fmaxf(accx/sd + bb.x, 0.f);
  float ry = fmaxf(accy/sd + bb.y, 0.f);
  unsigned int hp = (unsigned int)f2bf(rx) | ((unsigned int)f2bf(ry) << 16);
  hb[(size_t)node*64 + l] = hp;
}

// ---------- agg layer 2: 4 edges/instr (16-lane groups), uint2 gathers, fused weights ----------
__global__ __launch_bounds__(256) void agg2_kernel(const int* __restrict__ rowptr, const int* __restrict__ esrc,
                                                   const float* __restrict__ as2, const float* __restrict__ ad2,
                                                   const uint2* __restrict__ xb2,
                                                   const float* __restrict__ bmu, const float* __restrict__ bst,
                                                   float* __restrict__ out){
  int node = blockIdx.x*4 + (threadIdx.x>>6);
  int l = threadIdx.x & 63;
  if(node >= N_NODES) return;
  int g = l >> 4, c = l & 15;        // lane handles features 4c..4c+3 of edge (i+g)
  int beg = rowptr[node], end = rowptr[node+1];
  const float2* asp = (const float2*)as2;
  float2 adn = ((const float2*)ad2)[node];
  int n = end - beg;
  float a0=0.f, a1=0.f, a2=0.f, a3=0.f, smu=0.f, sst=0.f;
  int nquad = n >> 2;
  int mainq = nquad & ~3;

#define G2(j) int e##j = esrc[base + 4*j]; float2 aa##j = asp[e##j];
#define U2(j) uint2 u##j = xb2[(size_t)e##j*16 + c];
#define C2(j) { float wx = __expf(lrelu(aa##j.x + adn.x)); \
                float wy = __expf(lrelu(aa##j.y + adn.y)); \
                smu += wx; sst += wy; \
                float vv = (c < 8) ? wx : wy; \
                a0 += vv*lof(u##j.x); a1 += vv*hif(u##j.x); \
                a2 += vv*lof(u##j.y); a3 += vv*hif(u##j.y); }

  for(int qq = 0; qq < mainq; qq += 4){
    int base = beg + 4*qq + g;
    G2(0) G2(1) G2(2) G2(3)
    U2(0) U2(1) U2(2) U2(3)
    C2(0) C2(1) C2(2) C2(3)
  }
  for(int qq = mainq; qq < nquad; qq++){
    int base = beg + 4*qq + g;
    G2(0) U2(0) C2(0)
  }
  int tail = n & 3;
  if(g < tail){
    int idx = beg + 4*nquad + g;
    int e = esrc[idx];
    float2 aa = asp[e];
    uint2 u = xb2[(size_t)e*16 + c];
    float wx = __expf(lrelu(aa.x + adn.x));
    float wy = __expf(lrelu(aa.y + adn.y));
    smu += wx; sst += wy;
    float vv = (c < 8) ? wx : wy;
    a0 += vv*lof(u.x); a1 += vv*hif(u.x);
    a2 += vv*lof(u.y); a3 += vv*hif(u.y);
  }
#undef G2
#undef U2
#undef C2
  #pragma unroll
  for(int off = 16; off < 64; off <<= 1){
    smu += __shfl_xor(smu, off); sst += __shfl_xor(sst, off);
    a0 += __shfl_xor(a0, off); a1 += __shfl_xor(a1, off);
    a2 += __shfl_xor(a2, off); a3 += __shfl_xor(a3, off);
  }
  float sd = (c < 8) ? smu : sst;
  float4 bb = (c < 8) ? *(const float4*)(bmu + 4*c) : *(const float4*)(bst + 4*(c-8));
  float4 r;
  r.x = a0/sd + bb.x;
  r.y = a1/sd + bb.y;
  r.z = a2/sd + bb.z;
  r.w = a3/sd + bb.w;
  if(g == 0){
    float* dst = (c < 8) ? (out + (size_t)node*Z + 4*c)
                         : (out + (size_t)N_NODES*Z + (size_t)node*Z + 4*(c-8));
    *(float4*)dst = r;
  }
}

extern "C" void kernel_launch(void* const* d_in, const int* in_sizes, int n_in,
                              void* d_out, int out_size, void* d_ws, size_t ws_size,
                              hipStream_t stream){
  const float* x    = (const float*)d_in[0];
  const int*   edges= (const int*)d_in[1];
  const float* W1   = (const float*)d_in[2];
  const float* as1v = (const float*)d_in[3];
  const float* ad1v = (const float*)d_in[4];
  const float* b1   = (const float*)d_in[5];
  const float* Wmu  = (const float*)d_in[6];
  const float* asmu = (const float*)d_in[7];
  const float* admu = (const float*)d_in[8];
  const float* bmu  = (const float*)d_in[9];
  const float* Wst  = (const float*)d_in[10];
  const float* asst = (const float*)d_in[11];
  const float* adst = (const float*)d_in[12];
  const float* bst  = (const float*)d_in[13];
  float* out = (float*)d_out;

  char* p = (char*)d_ws;
  auto alloc = [&](size_t bytes)->char*{ char* r = p; p += (bytes + 255) & ~size_t(255); return r; };
  int*   M      = (int*)  alloc((size_t)MTOT*4);
  int*   Mpos   = (int*)  alloc((size_t)MTOT*4);
  int*   bsumM  = (int*)  alloc((size_t)MBS*4);
  int*   bpreM  = (int*)  alloc((size_t)MBS*4);
  int2*  etmp   = (int2*) alloc((size_t)ET*8);
  int*   esrc   = (int*)  alloc((size_t)ET*4);
  int*   rowptr = (int*)  alloc((size_t)(N_NODES+1)*4);
  unsigned short* Wb1 = (unsigned short*)alloc((size_t)128*KD*2);
  unsigned short* Wb2 = (unsigned short*)alloc((size_t)64*KD*2);
  unsigned short* xpb1 = (unsigned short*)alloc((size_t)N_NODES*128*2);
  float* as1    = (float*)alloc((size_t)N_NODES*2*4);
  float* ad1    = (float*)alloc((size_t)N_NODES*2*4);
  unsigned short* hb = (unsigned short*)alloc((size_t)N_NODES*128*2);
  float* as2    = (float*)alloc((size_t)N_NODES*2*4);
  float* ad2    = (float*)alloc((size_t)N_NODES*2*4);
  unsigned short* xpb2 = xpb1;                          // xpb1 dead after agg1

  bhistA_kernel  <<<NBLKA, 256, 0, stream>>>(edges, M);
  scanM1_kernel  <<<MBS, 256, 0, stream>>>(M, bsumM);
  scanM2_kernel  <<<1, 256, 0, stream>>>(bsumM, bpreM);
  scanM3_kernel  <<<MBS, 256, 0, stream>>>(M, bpreM, Mpos);
  bplaceA_kernel <<<NBLKA, 256, 0, stream>>>(edges, Mpos, etmp);
  bfin_kernel    <<<NBUCK, 256, 0, stream>>>(Mpos, etmp, rowptr, esrc);

  wconv_kernel   <<<(128*KD + 255)/256, 256, 0, stream>>>(W1, Wmu, Wst, Wb1, Wb2);

  mmt1_kernel <<<(N_NODES+63)/64, 256, 0, stream>>>(x, Wb1, as1v, ad1v, xpb1, as1, ad1);
  agg1_kernel <<<(N_NODES+3)/4, 256, 0, stream>>>(rowptr, esrc, as1, ad1, (const unsigned int*)xpb1, b1, (unsigned int*)hb);

  mmt2_kernel <<<(N_NODES+63)/64, 256, 0, stream>>>(hb, Wb2, asmu, admu, asst, adst, xpb1, as2, ad2);
  agg2_kernel <<<(N_NODES+3)/4, 256, 0, stream>>>(rowptr, esrc, as2, ad2, (const uint2*)xpb2, bmu, bst, out);
}